// Round 1
// baseline (9159.826 us; speedup 1.0000x reference)
//
#include <hip/hip_runtime.h>
#include <stdint.h>

// Problem dims
#define NB 512   // batch N
#define NM 64    // rows of G
#define NT 32    // tx antennas (and scan steps)
#define NK 8     // symbol alphabet
#define NS 256   // MC samples

// JAX default since ~0.4.30: threefry_partitionable=True
#define THREEFRY_PARTITIONABLE 1

__device__ __forceinline__ uint2 tf2x32(uint32_t k0, uint32_t k1, uint32_t x0, uint32_t x1) {
  uint32_t k2 = k0 ^ k1 ^ 0x1BD11BDAu;
#define TFRND(r) { x0 += x1; x1 = (x1 << (r)) | (x1 >> (32 - (r))); x1 ^= x0; }
  x0 += k0; x1 += k1;
  TFRND(13) TFRND(15) TFRND(26) TFRND(6)
  x0 += k1; x1 += k2 + 1u;
  TFRND(17) TFRND(29) TFRND(16) TFRND(24)
  x0 += k2; x1 += k0 + 2u;
  TFRND(13) TFRND(15) TFRND(26) TFRND(6)
  x0 += k0; x1 += k1 + 3u;
  TFRND(17) TFRND(29) TFRND(16) TFRND(24)
  x0 += k1; x1 += k2 + 4u;
  TFRND(13) TFRND(15) TFRND(26) TFRND(6)
  x0 += k2; x1 += k0 + 5u;
#undef TFRND
  return make_uint2(x0, x1);
}

// JAX uniform(minval=tiny, maxval=1) -> gumbel = -log(-log(u))
__device__ __forceinline__ float gumbel_from_bits(uint32_t bits) {
  const float TINY = 1.17549435e-38f;
  float f = __uint_as_float((bits >> 9) | 0x3f800000u) - 1.0f;
  float u = fmaxf(TINY, f + TINY);   // (1-tiny)==1 in f32, so mul omitted (exact)
  return -logf(-logf(u));
}

__global__ __launch_bounds__(256) void init_kernel(
    const float* __restrict__ log_qi, const float* __restrict__ G,
    const float* __restrict__ s2r, float* __restrict__ lq,
    float* __restrict__ sG, uint32_t* __restrict__ keys) {
  int i = blockIdx.x * 256 + threadIdx.x;
  if (i < NB * NM * NT) {
    int n = i >> 11;            // / (NM*NT = 2048)
    sG[i] = s2r[n] * G[i];      // sqrt_2rho[:,None,None] * G, exact f32 mul
  }
  if (i < NB * NT * NK) lq[i] = log_qi[i];
  if (i < NT) {
#if THREEFRY_PARTITIONABLE
    // split foldlike: key_i = threefry2x32(parent, hi=0, lo=i)
    uint2 r = tf2x32(0u, 42u, 0u, (uint32_t)i);
    keys[2 * i] = r.x; keys[2 * i + 1] = r.y;
#else
    // original split: bits = concat(y0(pairs), y1(pairs)) of iota(64)
    uint32_t w[2];
    for (int d = 0; d < 2; ++d) {
      int j = 2 * i + d;
      if (j < 32) { uint2 r = tf2x32(0u, 42u, (uint32_t)j, (uint32_t)(j + 32)); w[d] = r.x; }
      else        { uint2 r = tf2x32(0u, 42u, (uint32_t)(j - 32), (uint32_t)j); w[d] = r.y; }
    }
    keys[2 * i] = w[0]; keys[2 * i + 1] = w[1];
#endif
  }
}

// One thread per (s, n, t): 8 gumbels -> argmax -> symbol in {-7..7} as int8
__global__ __launch_bounds__(256) void sample_kernel(
    const float* __restrict__ lq, const uint32_t* __restrict__ keys,
    int8_t* __restrict__ sym, int xi) {
  int gid = blockIdx.x * 256 + threadIdx.x;       // = (s*NB + n)*NT + t
  int t = gid & (NT - 1);
  int n = (gid >> 5) & (NB - 1);
  uint32_t kA = keys[2 * xi], kB = keys[2 * xi + 1];
  const float* lrow = lq + (size_t)(n * NT + t) * NK;
  float l[NK];
#pragma unroll
  for (int k = 0; k < NK; ++k) l[k] = lrow[k];

  float best = -INFINITY; int bi = 0;
#if THREEFRY_PARTITIONABLE
  uint32_t p = (uint32_t)gid << 3;                // flat index into (S,N,T,K) gumbel array
#pragma unroll
  for (int k = 0; k < NK; ++k) {
    uint2 r = tf2x32(kA, kB, 0u, p + (uint32_t)k);
    float g = gumbel_from_bits(r.x ^ r.y);
    float v = l[k] + g;
    if (v > best) { best = v; bi = k; }           // first-max tie-break like argmax
  }
  sym[gid] = (int8_t)(2 * bi - 7);
#else
  // original counter mode: bits[p] = y0(p, p+2^24) for p<2^24 else y1(p-2^24, p).
  // Thread covers s<128 and also s+128 (shared threefry evals).
  int s2 = gid >> 14;                             // 0..127 (launch with half grid)
  (void)s2;
  uint32_t p = (uint32_t)gid << 3;
  float bestB = -INFINITY; int biB = 0;
#pragma unroll
  for (int k = 0; k < NK; ++k) {
    uint2 r = tf2x32(kA, kB, p + (uint32_t)k, p + (uint32_t)k + (1u << 24));
    float vA = l[k] + gumbel_from_bits(r.x);
    float vB = l[k] + gumbel_from_bits(r.y);
    if (vA > best)  { best = vA; bi = k; }
    if (vB > bestB) { bestB = vB; biB = k; }
  }
  sym[gid] = (int8_t)(2 * bi - 7);
  sym[gid + (1 << 22)] = (int8_t)(2 * biB - 7);   // (s+128)*NB*NT offset = 128*512*32
#endif
}

// Block per n: base = sum_{t != xi} sG*sym ; 8 symbol variants at antenna xi;
// sum_m log_sigmoid(1.702*term); reduce over s; damped update; per-row max shift.
__global__ __launch_bounds__(256) void update_kernel(
    float* __restrict__ lq, const float* __restrict__ sG,
    const int8_t* __restrict__ sym, const float* __restrict__ alpha_p, int xi) {
  __shared__ float sg_s[NM * NT];      // 8 KiB
  __shared__ double red[4][NK];
  __shared__ float lqrow[NT * NK];     // 256 floats
  int n = blockIdx.x;
  int tid = threadIdx.x;

  for (int i = tid; i < NM * NT; i += 256) sg_s[i] = sG[(size_t)n * NM * NT + i];
  lqrow[tid] = lq[(size_t)n * NT * NK + tid];
  __syncthreads();

  // this thread's sample row: sym[s][n][0..31]
  int s = tid;
  const int8_t* sp = sym + ((size_t)s * NB + n) * NT;
  float symv[NT];
  {
    int4 a = *reinterpret_cast<const int4*>(sp);
    int4 b = *reinterpret_cast<const int4*>(sp + 16);
    uint32_t w[8] = {(uint32_t)a.x, (uint32_t)a.y, (uint32_t)a.z, (uint32_t)a.w,
                     (uint32_t)b.x, (uint32_t)b.y, (uint32_t)b.z, (uint32_t)b.w};
#pragma unroll
    for (int j = 0; j < 8; ++j) {
#pragma unroll
      for (int byte = 0; byte < 4; ++byte)
        symv[4 * j + byte] = (float)((int8_t)((w[j] >> (8 * byte)) & 0xffu));
    }
  }
  symv[xi] = 0.0f;  // exclude antenna xi from the base sum (x + 0.0f is exact)

  float lp[NK];
#pragma unroll
  for (int k = 0; k < NK; ++k) lp[k] = 0.0f;

  for (int m = 0; m < NM; ++m) {
    float base = 0.0f;
#pragma unroll
    for (int t = 0; t < NT; ++t) base = fmaf(sg_s[m * NT + t], symv[t], base);
    float c = sg_s[m * NT + xi];
#pragma unroll
    for (int k = 0; k < NK; ++k) {
      float sk = (float)(2 * k - 7);
      float term = base + c * sk;
      float z = 1.702f * term;
      // jax.nn.log_sigmoid(z) = min(z,0) - log1p(exp(-|z|))
      float e = expf(-fabsf(z));
      lp[k] += fminf(z, 0.0f) - log1pf(e);
    }
  }

  // reduce lp over the 256 samples (f64 for accuracy)
  double v[NK];
#pragma unroll
  for (int k = 0; k < NK; ++k) v[k] = (double)lp[k];
#pragma unroll
  for (int off = 32; off >= 1; off >>= 1) {
#pragma unroll
    for (int k = 0; k < NK; ++k) v[k] += __shfl_down(v[k], off, 64);
  }
  int wave = tid >> 6, lane = tid & 63;
  if (lane == 0) {
#pragma unroll
    for (int k = 0; k < NK; ++k) red[wave][k] = v[k];
  }
  __syncthreads();
  if (tid < NK) {
    double sum = red[0][tid] + red[1][tid] + red[2][tid] + red[3][tid];
    float ex = (float)(sum * (1.0 / 256.0));
    float alpha = *alpha_p;
    float oldv = lqrow[xi * NK + tid];
    lqrow[xi * NK + tid] = (1.0f - alpha) * oldv + alpha * ex;
  }
  __syncthreads();
  // per-(n,t) max shift (exact ops; unchanged rows stay bit-exact)
  float vv = lqrow[tid];
  float mx = vv;
  mx = fmaxf(mx, __shfl_xor(mx, 1, 64));
  mx = fmaxf(mx, __shfl_xor(mx, 2, 64));
  mx = fmaxf(mx, __shfl_xor(mx, 4, 64));
  lq[(size_t)n * NT * NK + tid] = vv - mx;
}

extern "C" void kernel_launch(void* const* d_in, const int* in_sizes, int n_in,
                              void* d_out, int out_size, void* d_ws, size_t ws_size,
                              hipStream_t stream) {
  const float* log_qi = (const float*)d_in[0];
  const float* G      = (const float*)d_in[1];
  const float* s2r    = (const float*)d_in[2];
  const float* alpha  = (const float*)d_in[3];
  float* lq = (float*)d_out;                       // lq working buffer IS the output
  char* ws = (char*)d_ws;
  float*    sG   = (float*)ws;                                   // 4 MiB
  int8_t*   sym  = (int8_t*)(ws + (size_t)NB * NM * NT * 4);     // 4 MiB
  uint32_t* keys = (uint32_t*)(ws + (size_t)NB * NM * NT * 4 + (size_t)NS * NB * NT);

  init_kernel<<<4096, 256, 0, stream>>>(log_qi, G, s2r, lq, sG, keys);
  for (int xi = 0; xi < NT; ++xi) {
#if THREEFRY_PARTITIONABLE
    sample_kernel<<<(NS * NB * NT) / 256, 256, 0, stream>>>(lq, keys, sym, xi);
#else
    sample_kernel<<<(NS * NB * NT) / 512, 256, 0, stream>>>(lq, keys, sym, xi);
#endif
    update_kernel<<<NB, 256, 0, stream>>>(lq, sG, sym, alpha, xi);
  }
}

// Round 3
// 9150.746 us; speedup vs baseline: 1.0010x; 1.0010x over previous
//
#include <hip/hip_runtime.h>
#include <stdint.h>

// Problem dims
#define NB 512   // batch N
#define NM 64    // rows of G
#define NT 32    // tx antennas (and scan steps)
#define NK 8     // symbol alphabet
#define NS 256   // MC samples

// JAX default since ~0.4.30: threefry_partitionable=True (verified round 1: absmax 1.0)
#define THREEFRY_PARTITIONABLE 1

__device__ __forceinline__ uint2 tf2x32(uint32_t k0, uint32_t k1, uint32_t x0, uint32_t x1) {
  uint32_t k2 = k0 ^ k1 ^ 0x1BD11BDAu;
#define TFRND(r) { x0 += x1; x1 = (x1 << (r)) | (x1 >> (32 - (r))); x1 ^= x0; }
  x0 += k0; x1 += k1;
  TFRND(13) TFRND(15) TFRND(26) TFRND(6)
  x0 += k1; x1 += k2 + 1u;
  TFRND(17) TFRND(29) TFRND(16) TFRND(24)
  x0 += k2; x1 += k0 + 2u;
  TFRND(13) TFRND(15) TFRND(26) TFRND(6)
  x0 += k0; x1 += k1 + 3u;
  TFRND(17) TFRND(29) TFRND(16) TFRND(24)
  x0 += k1; x1 += k2 + 4u;
  TFRND(13) TFRND(15) TFRND(26) TFRND(6)
  x0 += k2; x1 += k0 + 5u;
#undef TFRND
  return make_uint2(x0, x1);
}

// JAX uniform(minval=tiny, maxval=1) -> gumbel = -log(-log(u))
__device__ __forceinline__ float gumbel_from_bits(uint32_t bits) {
  const float TINY = 1.17549435e-38f;
  float f = __uint_as_float((bits >> 9) | 0x3f800000u) - 1.0f;
  float u = fmaxf(TINY, f + TINY);   // (1-tiny)==1 in f32, so mul omitted (exact)
  return -logf(-logf(u));
}

__global__ __launch_bounds__(256) void init_kernel(
    const float* __restrict__ log_qi, const float* __restrict__ G,
    const float* __restrict__ s2r, float* __restrict__ lq,
    float* __restrict__ sG, uint32_t* __restrict__ keys) {
  int i = blockIdx.x * 256 + threadIdx.x;
  if (i < NB * NM * NT) {
    int n = i >> 11;            // / (NM*NT = 2048)
    sG[i] = s2r[n] * G[i];      // sqrt_2rho[:,None,None] * G, exact f32 mul
  }
  if (i < NB * NT * NK) lq[i] = log_qi[i];
  if (i < NT) {
#if THREEFRY_PARTITIONABLE
    // split foldlike: key_i = threefry2x32(parent, hi=0, lo=i)
    uint2 r = tf2x32(0u, 42u, 0u, (uint32_t)i);
    keys[2 * i] = r.x; keys[2 * i + 1] = r.y;
#else
    uint32_t w[2];
    for (int d = 0; d < 2; ++d) {
      int j = 2 * i + d;
      if (j < 32) { uint2 r = tf2x32(0u, 42u, (uint32_t)j, (uint32_t)(j + 32)); w[d] = r.x; }
      else        { uint2 r = tf2x32(0u, 42u, (uint32_t)(j - 32), (uint32_t)j); w[d] = r.y; }
    }
    keys[2 * i] = w[0]; keys[2 * i + 1] = w[1];
#endif
  }
}

// One thread per (s, n, t): 8 gumbels -> argmax -> symbol in {-7..7} as int8
__global__ __launch_bounds__(256) void sample_kernel(
    const float* __restrict__ lq, const uint32_t* __restrict__ keys,
    int8_t* __restrict__ sym, int xi) {
  int gid = blockIdx.x * 256 + threadIdx.x;       // = (s*NB + n)*NT + t
  int t = gid & (NT - 1);
  int n = (gid >> 5) & (NB - 1);
  uint32_t kA = keys[2 * xi], kB = keys[2 * xi + 1];
  const float* lrow = lq + (size_t)(n * NT + t) * NK;
  float l[NK];
#pragma unroll
  for (int k = 0; k < NK; ++k) l[k] = lrow[k];

  float best = -INFINITY; int bi = 0;
  uint32_t p = (uint32_t)gid << 3;                // flat index into (S,N,T,K) gumbel array
#pragma unroll
  for (int k = 0; k < NK; ++k) {
    uint2 r = tf2x32(kA, kB, 0u, p + (uint32_t)k);
    float g = gumbel_from_bits(r.x ^ r.y);
    float v = l[k] + g;
    if (v > best) { best = v; bi = k; }           // first-max tie-break like argmax
  }
  sym[gid] = (int8_t)(2 * bi - 7);
}

// Block per n: base = sum_{t != xi} sG*sym ; 8 symbol variants at antenna xi;
// sum_m log_sigmoid(1.702*term); reduce over s; damped update; per-row max shift.
// NOTE: symv[] must only ever be indexed with compile-time constants (rule #20:
// a runtime index like symv[xi] demotes the whole array to scratch — that was
// round 1's 7x slowdown, VGPR_Count=44). The xi exclusion is done at unpack
// time with a per-element select instead.
__global__ __launch_bounds__(256, 2) void update_kernel(
    float* __restrict__ lq, const float* __restrict__ sG,
    const int8_t* __restrict__ sym, const float* __restrict__ alpha_p, int xi) {
  __shared__ float sg_s[NM * NT];      // 8 KiB
  __shared__ double red[4][NK];
  __shared__ float lqrow[NT * NK];     // 256 floats
  int n = blockIdx.x;
  int tid = threadIdx.x;

  for (int i = tid; i < NM * NT; i += 256) sg_s[i] = sG[(size_t)n * NM * NT + i];
  lqrow[tid] = lq[(size_t)n * NT * NK + tid];
  __syncthreads();

  // this thread's sample row: sym[s][n][0..31]
  int s = tid;
  const int8_t* sp = sym + ((size_t)s * NB + n) * NT;
  float symv[NT];
  {
    int4 a = *reinterpret_cast<const int4*>(sp);
    int4 b = *reinterpret_cast<const int4*>(sp + 16);
    uint32_t w[8] = {(uint32_t)a.x, (uint32_t)a.y, (uint32_t)a.z, (uint32_t)a.w,
                     (uint32_t)b.x, (uint32_t)b.y, (uint32_t)b.z, (uint32_t)b.w};
#pragma unroll
    for (int j = 0; j < 8; ++j) {
#pragma unroll
      for (int byte = 0; byte < 4; ++byte) {
        int t = 4 * j + byte;
        float v = (float)((int8_t)((w[j] >> (8 * byte)) & 0xffu));
        symv[t] = (t == xi) ? 0.0f : v;   // static index, runtime compare -> cndmask
      }
    }
  }

  float lp[NK];
#pragma unroll
  for (int k = 0; k < NK; ++k) lp[k] = 0.0f;

  for (int m = 0; m < NM; ++m) {
    float base = 0.0f;
#pragma unroll
    for (int t = 0; t < NT; ++t) base = fmaf(sg_s[m * NT + t], symv[t], base);
    float c = sg_s[m * NT + xi];
#pragma unroll
    for (int k = 0; k < NK; ++k) {
      float sk = (float)(2 * k - 7);
      float term = base + c * sk;
      float z = 1.702f * term;
      // jax.nn.log_sigmoid(z) = min(z,0) - log1p(exp(-|z|))
      float e = expf(-fabsf(z));
      lp[k] += fminf(z, 0.0f) - log1pf(e);
    }
  }

  // reduce lp over the 256 samples (f64 for accuracy)
  double v[NK];
#pragma unroll
  for (int k = 0; k < NK; ++k) v[k] = (double)lp[k];
#pragma unroll
  for (int off = 32; off >= 1; off >>= 1) {
#pragma unroll
    for (int k = 0; k < NK; ++k) v[k] += __shfl_down(v[k], off, 64);
  }
  int wave = tid >> 6, lane = tid & 63;
  if (lane == 0) {
#pragma unroll
    for (int k = 0; k < NK; ++k) red[wave][k] = v[k];
  }
  __syncthreads();
  if (tid < NK) {
    double sum = red[0][tid] + red[1][tid] + red[2][tid] + red[3][tid];
    float ex = (float)(sum * (1.0 / 256.0));
    float alpha = *alpha_p;
    float oldv = lqrow[xi * NK + tid];
    lqrow[xi * NK + tid] = (1.0f - alpha) * oldv + alpha * ex;
  }
  __syncthreads();
  // per-(n,t) max shift (exact ops; unchanged rows stay bit-exact)
  float vv = lqrow[tid];
  float mx = vv;
  mx = fmaxf(mx, __shfl_xor(mx, 1, 64));
  mx = fmaxf(mx, __shfl_xor(mx, 2, 64));
  mx = fmaxf(mx, __shfl_xor(mx, 4, 64));
  lq[(size_t)n * NT * NK + tid] = vv - mx;
}

extern "C" void kernel_launch(void* const* d_in, const int* in_sizes, int n_in,
                              void* d_out, int out_size, void* d_ws, size_t ws_size,
                              hipStream_t stream) {
  const float* log_qi = (const float*)d_in[0];
  const float* G      = (const float*)d_in[1];
  const float* s2r    = (const float*)d_in[2];
  const float* alpha  = (const float*)d_in[3];
  float* lq = (float*)d_out;                       // lq working buffer IS the output
  char* ws = (char*)d_ws;
  float*    sG   = (float*)ws;                                   // 4 MiB
  int8_t*   sym  = (int8_t*)(ws + (size_t)NB * NM * NT * 4);     // 4 MiB
  uint32_t* keys = (uint32_t*)(ws + (size_t)NB * NM * NT * 4 + (size_t)NS * NB * NT);

  init_kernel<<<4096, 256, 0, stream>>>(log_qi, G, s2r, lq, sG, keys);
  for (int xi = 0; xi < NT; ++xi) {
    sample_kernel<<<(NS * NB * NT) / 256, 256, 0, stream>>>(lq, keys, sym, xi);
    update_kernel<<<NB, 256, 0, stream>>>(lq, sG, sym, alpha, xi);
  }
}